// Round 12
// baseline (52.986 us; speedup 1.0000x reference)
//
#include <hip/hip_runtime.h>
#include <math.h>

// B=4, X=128, T=256, HIDDEN=128, EMB=128, DH=32, LATENT=32, K=1024
// Outputs concat: u (131072), zt (1048576), px (524288)
//
// Algebra: u[b,t,x] = K0 + mz*mp*( ft_bt . M . fx_bx^T + ft_bt.a + bvec.fx_bx + c0 )
//   M[j,i] = sum_k zt_Wo[j,k] wc_k px_Wo[i,k]   (128x128)
//   a[j]   = sum_k zt_Wo[j,k] wc_k px_bo[k]
//   bvec[i]= sum_k zt_bo[k] wc_k px_Wo[i,k]
//   c0     = sum_k zt_bo[k] wc_k px_bo[k],  wc_k = wcd[k>>5]/32
//
// k1 (prep, 133 blocks): blocks 0-3 g-chains + Fx/FxT/Ft tables; block 4
//   wc,K0,a,bvec,c0; blocks 5..132 M tiles (redundant wc per block).
// k2 (main, 512 blocks): 0-383 feat GEMMs (read tables); 384-511 u via M.

#define WS_WC  0
#define WS_K0  32
#define WS_C0  33
#define WS_A   64
#define WS_BV  192
#define WS_FX  512
#define WS_FXT 66560
#define WS_FT  132608
#define WS_M   264192

struct P {
    const float *x, *t, *param;
    const float *p2e_W1, *p2e_b1, *p2e_W2, *p2e_b2;
    const float *e2ex_W, *e2ex_b, *e2et_W, *e2et_b;
    const float *px_Wx, *px_bx, *px_We, *px_be, *px_Wo, *px_bo, *px_mult;
    const float *zt_Wx, *zt_bx, *zt_We, *zt_be, *zt_Wo, *zt_bo, *zt_mult;
    const float *h0, *blk_W1, *blk_b1, *blk_Wc, *blk_bc, *blk_W2, *blk_b2;
    const float *d_W, *d_b;
    float *out_u, *out_zt, *out_px, *ws;
};

__device__ __forceinline__ void fma4(float4& a, float s, const float4& v) {
    a.x += s * v.x; a.y += s * v.y; a.z += s * v.z; a.w += s * v.w;
}

// out[j] = bias[j] + sum_k vin[k] * W[k*128+j]; 256 threads.
__device__ __forceinline__ void gemv_stage(
    const float* __restrict__ W, const float* __restrict__ bias,
    const float* vin, float* vout, float* partf, int tid)
{
    const int j4 = tid & 31;
    const int sl = tid >> 5;
    float4 a4 = make_float4(0.f, 0.f, 0.f, 0.f);
    const float* Wp = W + sl * 16 * 128 + j4 * 4;
    #pragma unroll
    for (int k = 0; k < 16; ++k)
        fma4(a4, vin[sl * 16 + k], *(const float4*)&Wp[k * 128]);
    *(float4*)&partf[sl * 128 + j4 * 4] = a4;
    __syncthreads();
    if (tid < 128) {
        float v = bias[tid];
        #pragma unroll
        for (int q = 0; q < 8; ++q) v += partf[q * 128 + tid];
        vout[tid] = v;
    }
    __syncthreads();
}

// sw chain -> wcl[32] (LDS); optionally write ws wc + K0.
__device__ __forceinline__ void compute_wc(
    const P& p, float* sA, float* sB, float* partf, float* wcl,
    int tid, bool write_ws)
{
    if (tid < 128) sA[tid] = p.h0[tid];
    __syncthreads();
    gemv_stage(p.blk_W1, p.blk_b1, sA, sB, partf, tid);   // sacc in sB
    if (tid < 128) {
        float w2 = 0.f;
        const float4* rp = (const float4*)&p.blk_W2[tid * 128];
        #pragma unroll
        for (int m4 = 0; m4 < 32; ++m4) {
            const float4 wv = rp[m4];
            const float4 dv = *(const float4*)&p.d_W[m4 * 4];
            w2 += wv.x * dv.x + wv.y * dv.y + wv.z * dv.z + wv.w * dv.w;
        }
        const float sv = __sinf(sB[tid]) * w2;
        sA[tid] = sv;                                     // sw
        sB[tid] = (p.h0[tid] + p.blk_b2[tid]) * p.d_W[tid] + sv * p.blk_bc[tid];
    }
    __syncthreads();
    {
        const int d  = tid >> 3;
        const int sg = (tid & 7) * 16;
        float acc = 0.f;
        #pragma unroll
        for (int i4 = 0; i4 < 4; ++i4) {
            const float4 wv = *(const float4*)&p.blk_Wc[d * 128 + sg + i4 * 4];
            const float4 sv = *(const float4*)&sA[sg + i4 * 4];
            acc += wv.x * sv.x + wv.y * sv.y + wv.z * sv.z + wv.w * sv.w;
        }
        partf[d * 8 + (tid & 7)] = acc;
    }
    __syncthreads();
    if (tid < 32) {
        float w = 0.f;
        #pragma unroll
        for (int q = 0; q < 8; ++q) w += partf[tid * 8 + q];
        wcl[tid] = w * (1.0f / 32.0f);
        if (write_ws) p.ws[WS_WC + tid] = wcl[tid];
    }
    if (write_ws) {
        if (tid < 64) sB[tid] += sB[tid + 64];
        __syncthreads();
        if (tid == 0) {
            float K = p.d_b[0];
            #pragma unroll
            for (int i = 0; i < 64; ++i) K += sB[i];
            p.ws[WS_K0] = K;
        }
    }
    __syncthreads();
}

__global__ __launch_bounds__(256, 2) void prep_kernel(P p) {
    __shared__ float sA[128], sB[128], sC[128], sD[128];
    __shared__ float partf[1024];
    __shared__ float wcl[32];
    __shared__ float wxl[128], bxl[128], wtl[128], btl[128];
    const int tid = threadIdx.x;
    const int bid = blockIdx.x;

    if (bid < 4) {
        const int b = bid;
        if (tid < 128) {
            float a = p.p2e_b1[tid];
            #pragma unroll
            for (int q = 0; q < 16; ++q)
                a += p.param[b * 16 + q] * p.p2e_W1[q * 128 + tid];
            sA[tid] = __sinf(a);
            wxl[tid] = p.px_Wx[tid]; bxl[tid] = p.px_bx[tid];
            wtl[tid] = p.zt_Wx[tid]; btl[tid] = p.zt_bx[tid];
        }
        __syncthreads();
        gemv_stage(p.p2e_W2, p.p2e_b2, sA, sB, partf, tid);   // e
        gemv_stage(p.e2ex_W, p.e2ex_b, sB, sC, partf, tid);   // ex
        gemv_stage(p.e2et_W, p.e2et_b, sB, sD, partf, tid);   // et
        gemv_stage(p.px_We,  p.px_be,  sC, sA, partf, tid);   // gx in sA
        gemv_stage(p.zt_We,  p.zt_be,  sD, sC, partf, tid);   // gt in sC

        const int j = tid & 127;
        const int h = tid >> 7;
        // Fx row-major [b][x][j]
        {
            const float wj = wxl[j], bj = bxl[j], g = sA[j];
            for (int xi = h * 64; xi < h * 64 + 64; ++xi)
                p.ws[WS_FX + b * 16384 + xi * 128 + j] =
                    __sinf(p.x[b * 128 + xi] * wj + bj) * g;
        }
        // FxT [b][j][x]
        {
            const float xc = p.x[b * 128 + j];
            for (int jj = h * 64; jj < h * 64 + 64; ++jj)
                p.ws[WS_FXT + b * 16384 + jj * 128 + j] =
                    __sinf(xc * wxl[jj] + bxl[jj]) * sA[jj];
        }
        // Ft row-major [b][t][j]
        {
            const float wj = wtl[j], bj = btl[j], g = sC[j];
            for (int ti = h * 128; ti < h * 128 + 128; ++ti)
                p.ws[WS_FT + b * 32768 + ti * 128 + j] =
                    __sinf(p.t[b * 256 + ti] * wj + bj) * g;
        }
    } else if (bid == 4) {
        __shared__ float wb[1024], zb[1024];
        compute_wc(p, sA, sB, partf, wcl, tid, true);
        {
            const int k4 = tid * 4;
            const float w = wcl[k4 >> 5];
            float4 bp = *(const float4*)&p.px_bo[k4];
            float4 bz = *(const float4*)&p.zt_bo[k4];
            float4 v1, v2;
            v1.x = w * bp.x; v1.y = w * bp.y; v1.z = w * bp.z; v1.w = w * bp.w;
            v2.x = w * bz.x; v2.y = w * bz.y; v2.z = w * bz.z; v2.w = w * bz.w;
            *(float4*)&wb[k4] = v1;          // wc*bp
            *(float4*)&zb[k4] = v2;          // wc*bz
            // c0 partial: (wc*bz).bp
            partf[tid] = v2.x * bp.x + v2.y * bp.y + v2.z * bp.z + v2.w * bp.w;
        }
        __syncthreads();
        if (tid < 128) {
            // a[j] = zt_Wo[j,:] . (wc*bp)
            float acc = 0.f;
            const float4* rp = (const float4*)&p.zt_Wo[tid * 1024];
            #pragma unroll 8
            for (int k4 = 0; k4 < 256; ++k4) {
                const float4 wv = rp[k4];
                const float4 cv = *(const float4*)&wb[k4 * 4];
                acc += wv.x * cv.x + wv.y * cv.y + wv.z * cv.z + wv.w * cv.w;
            }
            p.ws[WS_A + tid] = acc;
        } else {
            // bvec[i] = (wc*bz) . px_Wo[i,:]
            const int i = tid - 128;
            float acc = 0.f;
            const float4* rp = (const float4*)&p.px_Wo[i * 1024];
            #pragma unroll 8
            for (int k4 = 0; k4 < 256; ++k4) {
                const float4 wv = rp[k4];
                const float4 cv = *(const float4*)&zb[k4 * 4];
                acc += wv.x * cv.x + wv.y * cv.y + wv.z * cv.z + wv.w * cv.w;
            }
            p.ws[WS_BV + i] = acc;
        }
        // c0 reduce
        if (tid < 128) partf[tid] += partf[tid + 128];
        __syncthreads();
        if (tid < 64) partf[tid] += partf[tid + 64];
        __syncthreads();
        if (tid == 0) {
            float c = 0.f;
            #pragma unroll
            for (int i = 0; i < 64; ++i) c += partf[i];
            p.ws[WS_C0] = c;
        }
    } else {
        // M tile: 16 j x 8 i, k-split 2. mm in 0..127.
        compute_wc(p, sA, sB, partf, wcl, tid, false);
        const int mm = bid - 5;
        const int j0 = (mm >> 4) * 16;
        const int i0 = (mm & 15) * 8;
        const int o  = tid & 127;
        const int kh = tid >> 7;
        const int j  = j0 + (o >> 3);
        const int i  = i0 + (o & 7);
        float acc = 0.f;
        const float4* zp = (const float4*)&p.zt_Wo[j * 1024 + kh * 512];
        const float4* pp = (const float4*)&p.px_Wo[i * 1024 + kh * 512];
        #pragma unroll 8
        for (int k4 = 0; k4 < 128; ++k4) {
            const float4 zf = zp[k4];
            const float4 pf = pp[k4];
            const float w = wcl[(kh * 128 + k4) >> 3];
            acc += w * (zf.x * pf.x + zf.y * pf.y + zf.z * pf.z + zf.w * pf.w);
        }
        partf[kh * 128 + o] = acc;
        __syncthreads();
        if (tid < 128)
            p.ws[WS_M + j * 128 + i] = partf[tid] + partf[128 + tid];
    }
}

__global__ __launch_bounds__(256, 2) void main_kernel(P p) {
    __shared__ float f[8 * 128];          // feat f-rows / u ftl
    __shared__ float wl[8][132];
    __shared__ float atl[8];
    const int tid = threadIdx.x;
    const int bid = blockIdx.x;

    if (bid < 384) {
        // ================= feat =================
        const bool is_zt = bid >= 128;
        const int un = is_zt ? bid - 128 : bid;
        const int rt = un >> 1, cs = un & 1;
        const int r0 = rt * 8;
        const int b = is_zt ? (r0 >> 8) : (r0 >> 7);
        const int ri = is_zt ? (r0 & 255) : (r0 & 127);

        const float* Wo = is_zt ? p.zt_Wo : p.px_Wo;
        const float* bo = is_zt ? p.zt_bo : p.px_bo;
        const float mult = is_zt ? p.zt_mult[0] : p.px_mult[0];
        float* outp = is_zt ? p.out_zt : p.out_px;
        const float* ftab = p.ws + (is_zt ? (WS_FT + b * 32768) : (WS_FX + b * 16384));

        // stage f rows from table: 256 f4
        {
            const int row = tid >> 5, j4 = (tid & 31) * 4;
            *(float4*)&f[row * 128 + j4] =
                *(const float4*)&ftab[(ri + row) * 128 + j4];
        }
        __syncthreads();

        const int c = tid & 127;
        const int h = tid >> 7;
        const int c0 = cs * 512 + c * 4;
        const float* wp = Wo + c0;
        const float* fr = f + h * 4 * 128;

        float4 acc[4];
        #pragma unroll
        for (int rr = 0; rr < 4; ++rr) acc[rr] = make_float4(0.f, 0.f, 0.f, 0.f);

        float4 wA[8], wB[8];
        #pragma unroll
        for (int i = 0; i < 8; ++i) wA[i] = *(const float4*)&wp[i * 1024];

        #pragma unroll
        for (int g2 = 0; g2 < 8; ++g2) {
            #pragma unroll
            for (int i = 0; i < 8; ++i)
                wB[i] = *(const float4*)&wp[((2 * g2 + 1) * 8 + i) * 1024];
            {
                const int k0 = 16 * g2;
                #pragma unroll
                for (int rr = 0; rr < 4; ++rr) {
                    const float4 f0 = *(const float4*)&fr[rr * 128 + k0];
                    const float4 f1 = *(const float4*)&fr[rr * 128 + k0 + 4];
                    fma4(acc[rr], f0.x, wA[0]); fma4(acc[rr], f0.y, wA[1]);
                    fma4(acc[rr], f0.z, wA[2]); fma4(acc[rr], f0.w, wA[3]);
                    fma4(acc[rr], f1.x, wA[4]); fma4(acc[rr], f1.y, wA[5]);
                    fma4(acc[rr], f1.z, wA[6]); fma4(acc[rr], f1.w, wA[7]);
                }
            }
            if (g2 < 7) {
                #pragma unroll
                for (int i = 0; i < 8; ++i)
                    wA[i] = *(const float4*)&wp[((2 * g2 + 2) * 8 + i) * 1024];
            }
            {
                const int k0 = 16 * g2 + 8;
                #pragma unroll
                for (int rr = 0; rr < 4; ++rr) {
                    const float4 f0 = *(const float4*)&fr[rr * 128 + k0];
                    const float4 f1 = *(const float4*)&fr[rr * 128 + k0 + 4];
                    fma4(acc[rr], f0.x, wB[0]); fma4(acc[rr], f0.y, wB[1]);
                    fma4(acc[rr], f0.z, wB[2]); fma4(acc[rr], f0.w, wB[3]);
                    fma4(acc[rr], f1.x, wB[4]); fma4(acc[rr], f1.y, wB[5]);
                    fma4(acc[rr], f1.z, wB[6]); fma4(acc[rr], f1.w, wB[7]);
                }
            }
        }

        const float4 bias = *(const float4*)&bo[c0];
        #pragma unroll
        for (int rr = 0; rr < 4; ++rr) {
            float4 v;
            v.x = mult * (acc[rr].x + bias.x);
            v.y = mult * (acc[rr].y + bias.y);
            v.z = mult * (acc[rr].z + bias.z);
            v.w = mult * (acc[rr].w + bias.w);
            *(float4*)&outp[(r0 + h * 4 + rr) * 1024 + c0] = v;
        }
    } else {
        // ================= u via M =================
        const int m = bid - 384;           // 0..127
        const int b = m >> 5;
        const int t0 = (m & 31) * 8;
        const float* Ftb = p.ws + WS_FT + b * 32768;
        const float* FxTb = p.ws + WS_FXT + b * 16384;
        const float* Mb = p.ws + WS_M;

        // stage Ft rows (8x128)
        {
            const int row = tid >> 5, j4 = (tid & 31) * 4;
            *(float4*)&f[row * 128 + j4] =
                *(const float4*)&Ftb[(t0 + row) * 128 + j4];
        }
        __syncthreads();

        // W[r][jo] = sum_ji ftl[r][ji] * M[ji*128+jo]  (+bvec)
        const int r   = tid >> 5;          // 0..7
        const int jo4 = (tid & 31) * 4;
        {
            float4 acc = make_float4(0.f, 0.f, 0.f, 0.f);
            const float* frow = f + r * 128;
            #pragma unroll 8
            for (int ji = 0; ji < 128; ++ji)
                fma4(acc, frow[ji], *(const float4*)&Mb[ji * 128 + jo4]);
            const float4 bv = *(const float4*)&p.ws[WS_BV + jo4];
            acc.x += bv.x; acc.y += bv.y; acc.z += bv.z; acc.w += bv.w;
            *(float4*)&wl[r][jo4] = acc;
        }
        // At[r] = a . ftl[r]
        if (tid < 8) {
            const float* frow = f + tid * 128;
            float s = 0.f;
            #pragma unroll 8
            for (int j4 = 0; j4 < 32; ++j4) {
                const float4 av = *(const float4*)&p.ws[WS_A + j4 * 4];
                const float4 fv = *(const float4*)&frow[j4 * 4];
                s += av.x * fv.x + av.y * fv.y + av.z * fv.z + av.w * fv.w;
            }
            atl[tid] = s;
        }
        __syncthreads();

        // U[r][x] = K0 + mzmp*(c0 + At[r] + sum_j W'[r][j]*FxT[j][x])
        const int xg = tid & 31;           // x0 = xg*4
        const int rr = tid >> 5;           // 0..7 (same as r)
        const int x0 = xg * 4;
        float4 accX = make_float4(0.f, 0.f, 0.f, 0.f);
        #pragma unroll 4
        for (int j4 = 0; j4 < 32; ++j4) {
            const float4 w4 = *(const float4*)&wl[rr][j4 * 4];
            fma4(accX, w4.x, *(const float4*)&FxTb[(j4 * 4    ) * 128 + x0]);
            fma4(accX, w4.y, *(const float4*)&FxTb[(j4 * 4 + 1) * 128 + x0]);
            fma4(accX, w4.z, *(const float4*)&FxTb[(j4 * 4 + 2) * 128 + x0]);
            fma4(accX, w4.w, *(const float4*)&FxTb[(j4 * 4 + 3) * 128 + x0]);
        }
        const float mzmp = p.zt_mult[0] * p.px_mult[0];
        const float base = p.ws[WS_K0] + mzmp * (p.ws[WS_C0] + atl[rr]);
        float4 v;
        v.x = base + mzmp * accX.x; v.y = base + mzmp * accX.y;
        v.z = base + mzmp * accX.z; v.w = base + mzmp * accX.w;
        *(float4*)&p.out_u[(b * 256 + t0 + rr) * 128 + x0] = v;
    }
}

extern "C" void kernel_launch(void* const* d_in, const int* in_sizes, int n_in,
                              void* d_out, int out_size, void* d_ws, size_t ws_size,
                              hipStream_t stream) {
    float* out = (float*)d_out;

    P prm;
    prm.x       = (const float*)d_in[0];
    prm.t       = (const float*)d_in[1];
    prm.param   = (const float*)d_in[2];
    prm.p2e_W1  = (const float*)d_in[3];
    prm.p2e_b1  = (const float*)d_in[4];
    prm.p2e_W2  = (const float*)d_in[5];
    prm.p2e_b2  = (const float*)d_in[6];
    prm.e2ex_W  = (const float*)d_in[7];
    prm.e2ex_b  = (const float*)d_in[8];
    prm.e2et_W  = (const float*)d_in[9];
    prm.e2et_b  = (const float*)d_in[10];
    prm.px_Wx   = (const float*)d_in[11];
    prm.px_bx   = (const float*)d_in[12];
    prm.px_We   = (const float*)d_in[13];
    prm.px_be   = (const float*)d_in[14];
    prm.px_Wo   = (const float*)d_in[15];
    prm.px_bo   = (const float*)d_in[16];
    prm.px_mult = (const float*)d_in[17];
    prm.zt_Wx   = (const float*)d_in[18];
    prm.zt_bx   = (const float*)d_in[19];
    prm.zt_We   = (const float*)d_in[20];
    prm.zt_be   = (const float*)d_in[21];
    prm.zt_Wo   = (const float*)d_in[22];
    prm.zt_bo   = (const float*)d_in[23];
    prm.zt_mult = (const float*)d_in[24];
    prm.h0      = (const float*)d_in[25];
    prm.blk_W1  = (const float*)d_in[26];
    prm.blk_b1  = (const float*)d_in[27];
    prm.blk_Wc  = (const float*)d_in[28];
    prm.blk_bc  = (const float*)d_in[29];
    prm.blk_W2  = (const float*)d_in[30];
    prm.blk_b2  = (const float*)d_in[31];
    prm.d_W     = (const float*)d_in[32];
    prm.d_b     = (const float*)d_in[33];
    prm.out_u   = out;                        // 131072
    prm.out_zt  = out + 131072;               // 1048576
    prm.out_px  = out + 131072 + 1048576;     // 524288
    prm.ws      = (float*)d_ws;

    prep_kernel<<<133, 256, 0, stream>>>(prm);
    main_kernel<<<512, 256, 0, stream>>>(prm);
}